// Round 1
// baseline (5116.834 us; speedup 1.0000x reference)
//
#include <hip/hip_runtime.h>
#include <cstdint>

constexpr int BATCH = 32;
constexpr int DIMC  = 384;
constexpr int NTOK  = 784;
constexpr int KD    = 32;
constexpr int DV    = 128;
constexpr int PERH  = 192;   // per-head qkv channels (32 q + 32 k + 128 v)
constexpr int HQKV  = 1536;
constexpr int DHTOT = 1024;
constexpr float BNEPS  = 1e-5f;
constexpr float QSCALE = 0.17677669529663687f;  // 1/sqrt(32)
constexpr float LOG2E  = 1.4426950408889634f;

#define DEVFN static __device__ __forceinline__

DEVFN float hswish(float x) {
  float t = fminf(fmaxf(x + 3.0f, 0.0f), 6.0f);
  return x * t * (1.0f / 6.0f);
}
DEVFN float bf2f(uint16_t v) { return __uint_as_float(((uint32_t)v) << 16); }
DEVFN uint16_t f2bf(float f) {             // RNE bf16 truncation (finite inputs)
  uint32_t u = __float_as_uint(f);
  u += 0x7fffu + ((u >> 16) & 1u);
  return (uint16_t)(u >> 16);
}
DEVFN float4 load_bf16x4(const uint16_t* p) {   // p must be 8B aligned
  uint2 u = *reinterpret_cast<const uint2*>(p);
  float4 f;
  f.x = __uint_as_float(u.x << 16);
  f.y = __uint_as_float(u.x & 0xffff0000u);
  f.z = __uint_as_float(u.y << 16);
  f.w = __uint_as_float(u.y & 0xffff0000u);
  return f;
}

// ---------------- K1: QKV GEMM (fp32) + BN + hardswish (+SCALE into q), bf16 out
// grid (13, 12, nb)  block 256.  Y[o,n] = sum_c W[o,c] X[b,c,n]
__global__ __launch_bounds__(256) void qkv_kernel(
    const float* __restrict__ x, const float* __restrict__ w,
    const float* __restrict__ gw, const float* __restrict__ bw,
    const float* __restrict__ mw, const float* __restrict__ vw,
    uint16_t* __restrict__ y)
{
  const int b  = blockIdx.z;
  const int m0 = blockIdx.y * 128;
  const int n0 = blockIdx.x * 64;
  const float* X = x + (size_t)b * DIMC * NTOK;
  uint16_t* Y = y + (size_t)b * HQKV * NTOK;

  __shared__ float As[16][128];   // [k][m]
  __shared__ float Bs[16][68];    // [k][n]

  const int tid = threadIdx.x;
  const int tx = tid & 15;        // n group (4 cols)
  const int ty = tid >> 4;        // m group (8 rows)

  const int lmm = tid & 127;
  const int lkk = (tid >> 7) * 8;
  const int lbk = tid >> 4;
  const int lbn = (tid & 15) * 4;
  const bool bvalid = (n0 + lbn) < NTOK;
  const float* wrow = w + (size_t)(m0 + lmm) * DIMC;

  float acc[8][4];
  #pragma unroll
  for (int i = 0; i < 8; ++i)
    #pragma unroll
    for (int j = 0; j < 4; ++j) acc[i][j] = 0.f;

  for (int k0 = 0; k0 < DIMC; k0 += 16) {
    float4 a0 = *reinterpret_cast<const float4*>(wrow + k0 + lkk);
    float4 a1 = *reinterpret_cast<const float4*>(wrow + k0 + lkk + 4);
    float4 b4 = make_float4(0.f, 0.f, 0.f, 0.f);
    if (bvalid)
      b4 = *reinterpret_cast<const float4*>(X + (size_t)(k0 + lbk) * NTOK + n0 + lbn);
    __syncthreads();
    As[lkk+0][lmm] = a0.x; As[lkk+1][lmm] = a0.y; As[lkk+2][lmm] = a0.z; As[lkk+3][lmm] = a0.w;
    As[lkk+4][lmm] = a1.x; As[lkk+5][lmm] = a1.y; As[lkk+6][lmm] = a1.z; As[lkk+7][lmm] = a1.w;
    *reinterpret_cast<float4*>(&Bs[lbk][lbn]) = b4;
    __syncthreads();
    #pragma unroll
    for (int k = 0; k < 16; ++k) {
      float4 av0 = *reinterpret_cast<const float4*>(&As[k][ty*8]);
      float4 av1 = *reinterpret_cast<const float4*>(&As[k][ty*8+4]);
      float4 bv  = *reinterpret_cast<const float4*>(&Bs[k][tx*4]);
      float a[8] = {av0.x, av0.y, av0.z, av0.w, av1.x, av1.y, av1.z, av1.w};
      float bb[4] = {bv.x, bv.y, bv.z, bv.w};
      #pragma unroll
      for (int i = 0; i < 8; ++i)
        #pragma unroll
        for (int j = 0; j < 4; ++j) acc[i][j] += a[i] * bb[j];
    }
  }

  if (n0 + tx*4 < NTOK) {
    #pragma unroll
    for (int i = 0; i < 8; ++i) {
      int o = m0 + ty*8 + i;
      float sc = gw[o] * rsqrtf(vw[o] + BNEPS);
      float sh = bw[o] - mw[o] * sc;
      float qs = ((o % PERH) < KD) ? QSCALE : 1.0f;
      float v0 = hswish(acc[i][0]*sc + sh) * qs;
      float v1 = hswish(acc[i][1]*sc + sh) * qs;
      float v2 = hswish(acc[i][2]*sc + sh) * qs;
      float v3 = hswish(acc[i][3]*sc + sh) * qs;
      uint2 pk;
      pk.x = (uint32_t)f2bf(v0) | ((uint32_t)f2bf(v1) << 16);
      pk.y = (uint32_t)f2bf(v2) | ((uint32_t)f2bf(v3) << 16);
      *reinterpret_cast<uint2*>(Y + (size_t)o * NTOK + n0 + tx*4) = pk;
    }
  }
}

// ---------------- K2: flash attention over m-chunks of 64, 64 q-rows per block
// grid (13, nb*8)  block 256.  bias = attn_biases[h][|di|*28+|dj|] computed inline.
__global__ __launch_bounds__(256) void attn_kernel(
    const uint16_t* __restrict__ y, const float* __restrict__ biases,
    uint16_t* __restrict__ a2)
{
  const int bh = blockIdx.y;
  const int b = bh >> 3;
  const int h = bh & 7;
  const int n0 = blockIdx.x * 64;

  const uint16_t* Q  = y + ((size_t)b * HQKV + (size_t)h * PERH) * NTOK;
  const uint16_t* Kp = Q + (size_t)KD * NTOK;
  const uint16_t* Vp = Q + (size_t)(2*KD) * NTOK;
  uint16_t* Op = a2 + ((size_t)b * DHTOT + (size_t)h * DV) * NTOK;

  __shared__ float    kl[KD][68];      // k chunk   [d][m]
  __shared__ uint16_t vl16[64][136];   // v chunk transposed [m][d], bf16
  __shared__ float    pl[64][68];      // scores / probs [row][m]
  __shared__ float    ql[KD][64];      // q tile [d][row]
  __shared__ float    biasl[NTOK];
  __shared__ float    Mrow[64], Lrow[64], alphal[64];

  const int tid  = threadIdx.x;
  const int wave = tid >> 6;
  const int lane = tid & 63;
  const int tg   = tid >> 4;      // 0..15: row group of 4
  const int tl   = tid & 15;      // 0..15: col group

  for (int i = tid; i < NTOK; i += 256) biasl[i] = biases[(size_t)h * NTOK + i];
  for (int i = tid; i < KD*64; i += 256) {
    int d = i >> 6, r = i & 63;
    int n = n0 + r;
    ql[d][r] = (n < NTOK) ? bf2f(Q[(size_t)d * NTOK + n]) : 0.f;
  }
  if (tid < 64) { Mrow[tid] = -1e30f; Lrow[tid] = 0.f; }

  int ri[4], rj[4];
  #pragma unroll
  for (int i = 0; i < 4; ++i) {
    int n = n0 + tg*4 + i;
    int nn = (n < NTOK) ? n : 0;
    ri[i] = nn / 28; rj[i] = nn - ri[i]*28;
  }

  float acc[4][8];
  #pragma unroll
  for (int i = 0; i < 4; ++i)
    #pragma unroll
    for (int j = 0; j < 8; ++j) acc[i][j] = 0.f;

  for (int c = 0; c < 13; ++c) {
    const int mbase = c * 64;
    __syncthreads();   // prev PV done / init visible before restaging
    for (int i = tid; i < KD*64; i += 256) {
      int d = i >> 6, m = i & 63;
      int gm = mbase + m;
      kl[d][m] = (gm < NTOK) ? bf2f(Kp[(size_t)d * NTOK + gm]) : 0.f;
    }
    for (int i = tid; i < DV*64; i += 256) {
      int d = i >> 6, m = i & 63;
      int gm = mbase + m;
      vl16[m][d] = (gm < NTOK) ? Vp[(size_t)d * NTOK + gm] : (uint16_t)0;
    }
    __syncthreads();

    // ---- scores: 4 rows x 4 cols per thread, K=32
    {
      float s[4][4];
      #pragma unroll
      for (int i = 0; i < 4; ++i)
        #pragma unroll
        for (int j = 0; j < 4; ++j) s[i][j] = 0.f;
      #pragma unroll
      for (int d = 0; d < KD; ++d) {
        float4 qv = *reinterpret_cast<const float4*>(&ql[d][tg*4]);
        float4 kv = *reinterpret_cast<const float4*>(&kl[d][tl*4]);
        float qa[4] = {qv.x, qv.y, qv.z, qv.w};
        float ka[4] = {kv.x, kv.y, kv.z, kv.w};
        #pragma unroll
        for (int i = 0; i < 4; ++i)
          #pragma unroll
          for (int j = 0; j < 4; ++j) s[i][j] += qa[i] * ka[j];
      }
      #pragma unroll
      for (int j = 0; j < 4; ++j) {
        int m = mbase + tl*4 + j;
        bool mv = m < NTOK;
        int im = 0, jm = 0;
        if (mv) { im = (m * 2341) >> 16; jm = m - im*28; }  // m/28, m%28
        #pragma unroll
        for (int i = 0; i < 4; ++i) {
          float sv = -1e30f;
          if (mv) {
            int di = ri[i] - im; di = (di < 0) ? -di : di;
            int dj = rj[i] - jm; dj = (dj < 0) ? -dj : dj;
            sv = s[i][j] + biasl[di*28 + dj];
          }
          s[i][j] = sv;
        }
      }
      #pragma unroll
      for (int i = 0; i < 4; ++i)
        *reinterpret_cast<float4*>(&pl[tg*4+i][tl*4]) =
            make_float4(s[i][0], s[i][1], s[i][2], s[i][3]);
    }
    __syncthreads();

    // ---- online softmax: wave w owns rows 16w..16w+15
    for (int rr = 0; rr < 16; ++rr) {
      int r = wave * 16 + rr;
      float sv = pl[r][lane];
      float mx = sv;
      #pragma unroll
      for (int off = 32; off > 0; off >>= 1) mx = fmaxf(mx, __shfl_xor(mx, off));
      float Mo = Mrow[r];
      float Mn = fmaxf(Mo, mx);
      float p = exp2f((sv - Mn) * LOG2E);
      float sum = p;
      #pragma unroll
      for (int off = 32; off > 0; off >>= 1) sum += __shfl_xor(sum, off);
      pl[r][lane] = p;
      if (lane == 0) {
        float al = exp2f((Mo - Mn) * LOG2E);
        Mrow[r] = Mn;
        Lrow[r] = Lrow[r] * al + sum;
        alphal[r] = al;
      }
    }
    __syncthreads();

    // ---- PV accumulate: rows tg*4.., d = tl*8..
    {
      #pragma unroll
      for (int i = 0; i < 4; ++i) {
        float al = alphal[tg*4 + i];
        #pragma unroll
        for (int j = 0; j < 8; ++j) acc[i][j] *= al;
      }
      for (int m4 = 0; m4 < 64; m4 += 4) {
        float4 p0 = *reinterpret_cast<const float4*>(&pl[tg*4+0][m4]);
        float4 p1 = *reinterpret_cast<const float4*>(&pl[tg*4+1][m4]);
        float4 p2 = *reinterpret_cast<const float4*>(&pl[tg*4+2][m4]);
        float4 p3 = *reinterpret_cast<const float4*>(&pl[tg*4+3][m4]);
        float pr[4][4] = {{p0.x,p0.y,p0.z,p0.w},{p1.x,p1.y,p1.z,p1.w},
                          {p2.x,p2.y,p2.z,p2.w},{p3.x,p3.y,p3.z,p3.w}};
        #pragma unroll
        for (int mm = 0; mm < 4; ++mm) {
          uint4 u = *reinterpret_cast<const uint4*>(&vl16[m4+mm][tl*8]);
          float va[8];
          va[0] = __uint_as_float(u.x << 16); va[1] = __uint_as_float(u.x & 0xffff0000u);
          va[2] = __uint_as_float(u.y << 16); va[3] = __uint_as_float(u.y & 0xffff0000u);
          va[4] = __uint_as_float(u.z << 16); va[5] = __uint_as_float(u.z & 0xffff0000u);
          va[6] = __uint_as_float(u.w << 16); va[7] = __uint_as_float(u.w & 0xffff0000u);
          #pragma unroll
          for (int i = 0; i < 4; ++i)
            #pragma unroll
            for (int j = 0; j < 8; ++j) acc[i][j] += pr[i][mm] * va[j];
        }
      }
    }
  }

  // epilogue: normalize, hardswish (pre-proj activation), store bf16
  #pragma unroll
  for (int i = 0; i < 4; ++i) {
    int n = n0 + tg*4 + i;
    if (n < NTOK) {
      float li = 1.0f / Lrow[tg*4 + i];
      #pragma unroll
      for (int j = 0; j < 8; ++j) {
        int d = tl*8 + j;
        Op[(size_t)d * NTOK + n] = f2bf(hswish(acc[i][j] * li));
      }
    }
  }
}

// ---------------- K3: proj GEMM (bf16 in, fp32 compute) + BN + hardswish, fp32 out
// grid (13, 3, nb) block 256
__global__ __launch_bounds__(256) void proj_kernel(
    const uint16_t* __restrict__ a2, const float* __restrict__ w,
    const float* __restrict__ gw, const float* __restrict__ bw,
    const float* __restrict__ mw, const float* __restrict__ vw,
    float* __restrict__ out)
{
  const int b  = blockIdx.z;
  const int m0 = blockIdx.y * 128;
  const int n0 = blockIdx.x * 64;
  const uint16_t* A2 = a2 + (size_t)b * DHTOT * NTOK;
  float* O = out + (size_t)b * DIMC * NTOK;

  __shared__ float As[16][128];
  __shared__ float Bs[16][68];

  const int tid = threadIdx.x;
  const int tx = tid & 15;
  const int ty = tid >> 4;

  const int lmm = tid & 127;
  const int lkk = (tid >> 7) * 8;
  const int lbk = tid >> 4;
  const int lbn = (tid & 15) * 4;
  const bool bvalid = (n0 + lbn) < NTOK;
  const float* wrow = w + (size_t)(m0 + lmm) * DHTOT;

  float acc[8][4];
  #pragma unroll
  for (int i = 0; i < 8; ++i)
    #pragma unroll
    for (int j = 0; j < 4; ++j) acc[i][j] = 0.f;

  for (int k0 = 0; k0 < DHTOT; k0 += 16) {
    float4 a0 = *reinterpret_cast<const float4*>(wrow + k0 + lkk);
    float4 a1 = *reinterpret_cast<const float4*>(wrow + k0 + lkk + 4);
    float4 b4 = make_float4(0.f, 0.f, 0.f, 0.f);
    if (bvalid)
      b4 = load_bf16x4(A2 + (size_t)(k0 + lbk) * NTOK + n0 + lbn);
    __syncthreads();
    As[lkk+0][lmm] = a0.x; As[lkk+1][lmm] = a0.y; As[lkk+2][lmm] = a0.z; As[lkk+3][lmm] = a0.w;
    As[lkk+4][lmm] = a1.x; As[lkk+5][lmm] = a1.y; As[lkk+6][lmm] = a1.z; As[lkk+7][lmm] = a1.w;
    *reinterpret_cast<float4*>(&Bs[lbk][lbn]) = b4;
    __syncthreads();
    #pragma unroll
    for (int k = 0; k < 16; ++k) {
      float4 av0 = *reinterpret_cast<const float4*>(&As[k][ty*8]);
      float4 av1 = *reinterpret_cast<const float4*>(&As[k][ty*8+4]);
      float4 bv  = *reinterpret_cast<const float4*>(&Bs[k][tx*4]);
      float a[8] = {av0.x, av0.y, av0.z, av0.w, av1.x, av1.y, av1.z, av1.w};
      float bb[4] = {bv.x, bv.y, bv.z, bv.w};
      #pragma unroll
      for (int i = 0; i < 8; ++i)
        #pragma unroll
        for (int j = 0; j < 4; ++j) acc[i][j] += a[i] * bb[j];
    }
  }

  if (n0 + tx*4 < NTOK) {
    #pragma unroll
    for (int i = 0; i < 8; ++i) {
      int o = m0 + ty*8 + i;
      float sc = gw[o] * rsqrtf(vw[o] + BNEPS);
      float sh = bw[o] - mw[o] * sc;
      float4 r;
      r.x = hswish(acc[i][0]*sc + sh);
      r.y = hswish(acc[i][1]*sc + sh);
      r.z = hswish(acc[i][2]*sc + sh);
      r.w = hswish(acc[i][3]*sc + sh);
      *reinterpret_cast<float4*>(O + (size_t)o * NTOK + n0 + tx*4) = r;
    }
  }
}

extern "C" void kernel_launch(void* const* d_in, const int* in_sizes, int n_in,
                              void* d_out, int out_size, void* d_ws, size_t ws_size,
                              hipStream_t stream)
{
  const float* x  = (const float*)d_in[0];
  const float* qw = (const float*)d_in[1];
  const float* qg = (const float*)d_in[2];
  const float* qb = (const float*)d_in[3];
  const float* qm = (const float*)d_in[4];
  const float* qv = (const float*)d_in[5];
  const float* ab = (const float*)d_in[6];
  const float* pw = (const float*)d_in[7];
  const float* pg = (const float*)d_in[8];
  const float* pb = (const float*)d_in[9];
  const float* pm = (const float*)d_in[10];
  const float* pv = (const float*)d_in[11];
  float* out = (float*)d_out;

  const size_t Y_PER_B  = (size_t)HQKV * NTOK;   // elements per batch in ws
  const size_t A2_PER_B = (size_t)DHTOT * NTOK;
  const size_t per_b_bytes = (Y_PER_B + A2_PER_B) * sizeof(uint16_t);

  int nb = (int)(ws_size / per_b_bytes);
  if (nb > BATCH) nb = BATCH;
  if (nb < 1) nb = 1;   // assume ws can hold at least one batch

  uint16_t* ybuf = (uint16_t*)d_ws;
  uint16_t* a2   = ybuf + (size_t)nb * Y_PER_B;

  for (int b0 = 0; b0 < BATCH; b0 += nb) {
    int cb = BATCH - b0; if (cb > nb) cb = nb;
    const float* xb = x + (size_t)b0 * DIMC * NTOK;
    float* ob = out + (size_t)b0 * DIMC * NTOK;

    qkv_kernel<<<dim3(13, 12, cb), 256, 0, stream>>>(xb, qw, qg, qb, qm, qv, ybuf);
    attn_kernel<<<dim3(13, cb * 8), 256, 0, stream>>>(ybuf, ab, a2);
    proj_kernel<<<dim3(13, 3, cb), 256, 0, stream>>>(a2, pw, pg, pb, pm, pv, ob);
  }
}

// Round 2
// 1056.553 us; speedup vs baseline: 4.8430x; 4.8430x over previous
//
#include <hip/hip_runtime.h>
#include <cstdint>

constexpr int BATCH = 32;
constexpr int DIMC  = 384;
constexpr int NTOK  = 784;
constexpr int KD    = 32;
constexpr int DV    = 128;
constexpr int PERH  = 192;
constexpr int HQKV  = 1536;
constexpr int DHTOT = 1024;
constexpr float BNEPS  = 1e-5f;
constexpr float QSCALE = 0.17677669529663687f;  // 1/sqrt(32)
constexpr float LOG2E  = 1.4426950408889634f;

#define DEVFN static __device__ __forceinline__

using f16x8 = __attribute__((ext_vector_type(8))) _Float16;
using f32x4 = __attribute__((ext_vector_type(4))) float;

DEVFN float hswish(float x) {
  float t = fminf(fmaxf(x + 3.0f, 0.0f), 6.0f);
  return x * t * (1.0f / 6.0f);
}
DEVFN uint16_t f2h(float f) { return __builtin_bit_cast(uint16_t, (_Float16)f); }
DEVFN float h2f(uint16_t u) { return (float)__builtin_bit_cast(_Float16, u); }
DEVFN float4 load_h4(const uint16_t* p) {   // 4 fp16 -> float4 (p 8B aligned)
  uint2 u = *reinterpret_cast<const uint2*>(p);
  float4 f;
  f.x = h2f((uint16_t)(u.x & 0xffffu));
  f.y = h2f((uint16_t)(u.x >> 16));
  f.z = h2f((uint16_t)(u.y & 0xffffu));
  f.w = h2f((uint16_t)(u.y >> 16));
  return f;
}

// ---------------- K1: QKV GEMM (fp32) + BN + hardswish (+SCALE into q)
// outputs: Q,K as [bh][n][32] fp16 ; V as [bh][d=128][n] fp16
// grid (13, 12, nb)  block 256
__global__ __launch_bounds__(256) void qkv_kernel(
    const float* __restrict__ x, const float* __restrict__ w,
    const float* __restrict__ gw, const float* __restrict__ bw,
    const float* __restrict__ mw, const float* __restrict__ vw,
    uint16_t* __restrict__ qb, uint16_t* __restrict__ kb, uint16_t* __restrict__ vb)
{
  const int b  = blockIdx.z;
  const int m0 = blockIdx.y * 128;
  const int n0 = blockIdx.x * 64;
  const float* X = x + (size_t)b * DIMC * NTOK;

  __shared__ float As[16][128];
  __shared__ float Bs[16][68];

  const int tid = threadIdx.x;
  const int tx = tid & 15;
  const int ty = tid >> 4;

  const int lmm = tid & 127;
  const int lkk = (tid >> 7) * 8;
  const int lbk = tid >> 4;
  const int lbn = (tid & 15) * 4;
  const bool bvalid = (n0 + lbn) < NTOK;
  const float* wrow = w + (size_t)(m0 + lmm) * DIMC;

  float acc[8][4];
  #pragma unroll
  for (int i = 0; i < 8; ++i)
    #pragma unroll
    for (int j = 0; j < 4; ++j) acc[i][j] = 0.f;

  for (int k0 = 0; k0 < DIMC; k0 += 16) {
    float4 a0 = *reinterpret_cast<const float4*>(wrow + k0 + lkk);
    float4 a1 = *reinterpret_cast<const float4*>(wrow + k0 + lkk + 4);
    float4 b4 = make_float4(0.f, 0.f, 0.f, 0.f);
    if (bvalid)
      b4 = *reinterpret_cast<const float4*>(X + (size_t)(k0 + lbk) * NTOK + n0 + lbn);
    __syncthreads();
    As[lkk+0][lmm] = a0.x; As[lkk+1][lmm] = a0.y; As[lkk+2][lmm] = a0.z; As[lkk+3][lmm] = a0.w;
    As[lkk+4][lmm] = a1.x; As[lkk+5][lmm] = a1.y; As[lkk+6][lmm] = a1.z; As[lkk+7][lmm] = a1.w;
    *reinterpret_cast<float4*>(&Bs[lbk][lbn]) = b4;
    __syncthreads();
    #pragma unroll
    for (int k = 0; k < 16; ++k) {
      float4 av0 = *reinterpret_cast<const float4*>(&As[k][ty*8]);
      float4 av1 = *reinterpret_cast<const float4*>(&As[k][ty*8+4]);
      float4 bv  = *reinterpret_cast<const float4*>(&Bs[k][tx*4]);
      float a[8] = {av0.x, av0.y, av0.z, av0.w, av1.x, av1.y, av1.z, av1.w};
      float bb[4] = {bv.x, bv.y, bv.z, bv.w};
      #pragma unroll
      for (int i = 0; i < 8; ++i)
        #pragma unroll
        for (int j = 0; j < 4; ++j) acc[i][j] += a[i] * bb[j];
    }
  }

  const int nb_ = n0 + tx*4;
  if (nb_ < NTOK) {
    float vals[8][4];
    const int o0 = m0 + ty*8;           // 8 contiguous channels, never cross a 32-seg
    #pragma unroll
    for (int i = 0; i < 8; ++i) {
      int o = o0 + i;
      float sc = gw[o] * rsqrtf(vw[o] + BNEPS);
      float sh = bw[o] - mw[o] * sc;
      #pragma unroll
      for (int j = 0; j < 4; ++j) vals[i][j] = hswish(acc[i][j]*sc + sh);
    }
    const int h  = o0 / PERH;
    const int r0 = o0 - h*PERH;
    const int bh = b*8 + h;
    if (r0 < KD) {
      #pragma unroll
      for (int i = 0; i < 8; ++i)
        #pragma unroll
        for (int j = 0; j < 4; ++j) vals[i][j] *= QSCALE;
    }
    if (r0 < 2*KD) {
      uint16_t* base = (r0 < KD) ? qb : kb;
      const int dd = r0 & (KD-1);
      #pragma unroll
      for (int j = 0; j < 4; ++j) {
        uint4 pk;
        pk.x = (uint32_t)f2h(vals[0][j]) | ((uint32_t)f2h(vals[1][j]) << 16);
        pk.y = (uint32_t)f2h(vals[2][j]) | ((uint32_t)f2h(vals[3][j]) << 16);
        pk.z = (uint32_t)f2h(vals[4][j]) | ((uint32_t)f2h(vals[5][j]) << 16);
        pk.w = (uint32_t)f2h(vals[6][j]) | ((uint32_t)f2h(vals[7][j]) << 16);
        *reinterpret_cast<uint4*>(base + ((size_t)bh*NTOK + nb_+j)*KD + dd) = pk;
      }
    } else {
      const int dv0 = r0 - 2*KD;
      #pragma unroll
      for (int i = 0; i < 8; ++i) {
        uint2 pk;
        pk.x = (uint32_t)f2h(vals[i][0]) | ((uint32_t)f2h(vals[i][1]) << 16);
        pk.y = (uint32_t)f2h(vals[i][2]) | ((uint32_t)f2h(vals[i][3]) << 16);
        *reinterpret_cast<uint2*>(vb + ((size_t)bh*DV + dv0+i)*NTOK + nb_) = pk;
      }
    }
  }
}

// ---------------- K2: MFMA flash attention. 4 waves/block, 16 q-rows/wave.
// S^T = mfma(K, Q): lane holds S[n = lane&15][m = 16t+4*(lane>>4)+r].
// P^T through per-wave LDS -> B operand of O^T = mfma(V, P).
// grid (13, nb*8)  block 256
__global__ __launch_bounds__(256) void attn_kernel(
    const uint16_t* __restrict__ Qb, const uint16_t* __restrict__ Kb,
    const uint16_t* __restrict__ Vb, const float* __restrict__ biases,
    uint16_t* __restrict__ a2)
{
  const int bh = blockIdx.y;
  const int h  = bh & 7;
  const int n0 = blockIdx.x * 64;

  __shared__ float biasl[NTOK];
  __shared__ __align__(16) uint16_t plds[4][16][72];   // [wave][n][m(64)+pad]

  const int tid = threadIdx.x;
  const int w   = tid >> 6;
  const int l   = tid & 63;
  const int lg  = l >> 4;
  const int ln  = l & 15;

  for (int i = tid; i < NTOK; i += 256) biasl[i] = biases[(size_t)h*NTOK + i];

  const int nraw   = n0 + 16*w + ln;
  const bool nvalid = nraw < NTOK;
  const int n  = nvalid ? nraw : (NTOK-1);
  const int ri = (n * 2341) >> 16;       // n/28
  const int rj = n - ri*28;

  const f16x8 qf = *reinterpret_cast<const f16x8*>(Qb + ((size_t)bh*NTOK + n)*KD + 8*lg);

  float M = -1e30f, L = 0.f;
  f32x4 acc[8];
  #pragma unroll
  for (int dt = 0; dt < 8; ++dt) acc[dt] = (f32x4){0.f, 0.f, 0.f, 0.f};

  __syncthreads();   // biasl ready

  for (int mb = 0; mb < NTOK; mb += 64) {
    const int rem   = (NTOK - mb) >> 4;
    const int ntile = rem < 4 ? rem : 4;

    float p[16];
    #pragma unroll
    for (int i = 0; i < 16; ++i) p[i] = -1e30f;

    #pragma unroll
    for (int t = 0; t < 4; ++t) {
      if (t < ntile) {
        f16x8 kf = *reinterpret_cast<const f16x8*>(
            Kb + ((size_t)bh*NTOK + mb + 16*t + ln)*KD + 8*lg);
        f32x4 st = __builtin_amdgcn_mfma_f32_16x16x32_f16(
            kf, qf, (f32x4){0.f,0.f,0.f,0.f}, 0, 0, 0);
        #pragma unroll
        for (int r = 0; r < 4; ++r) {
          int m  = mb + 16*t + 4*lg + r;
          int im = (m * 2341) >> 16;
          int jm = m - im*28;
          int di = ri - im; di = di < 0 ? -di : di;
          int dj = rj - jm; dj = dj < 0 ? -dj : dj;
          p[4*t + r] = st[r] + biasl[di*28 + dj];
        }
      }
    }

    float mx = p[0];
    #pragma unroll
    for (int i = 1; i < 16; ++i) mx = fmaxf(mx, p[i]);
    mx = fmaxf(mx, __shfl_xor(mx, 16));
    mx = fmaxf(mx, __shfl_xor(mx, 32));

    float Mn = fmaxf(M, mx);
    float al = exp2f((M - Mn) * LOG2E);
    float sum = 0.f;
    #pragma unroll
    for (int i = 0; i < 16; ++i) { p[i] = exp2f((p[i] - Mn) * LOG2E); sum += p[i]; }
    sum += __shfl_xor(sum, 16);
    sum += __shfl_xor(sum, 32);
    L = L * al + sum;
    M = Mn;
    #pragma unroll
    for (int dt = 0; dt < 8; ++dt) acc[dt] *= al;

    #pragma unroll
    for (int t = 0; t < 4; ++t) {
      uint2 pk;
      pk.x = (uint32_t)f2h(p[4*t+0]) | ((uint32_t)f2h(p[4*t+1]) << 16);
      pk.y = (uint32_t)f2h(p[4*t+2]) | ((uint32_t)f2h(p[4*t+3]) << 16);
      *reinterpret_cast<uint2*>(&plds[w][ln][16*t + 4*lg]) = pk;
    }
    __syncthreads();   // orders per-wave P writes before reads (and keeps waves together)

    #pragma unroll
    for (int ks = 0; ks < 2; ++ks) {
      f16x8 pf = *reinterpret_cast<const f16x8*>(&plds[w][ln][32*ks + 8*lg]);
      int mload = mb + 32*ks + 8*lg;
      if (mload > NTOK-8) mload = NTOK-8;   // clamp; P=0 there
      #pragma unroll
      for (int dt = 0; dt < 8; ++dt) {
        f16x8 vf = *reinterpret_cast<const f16x8*>(
            Vb + ((size_t)bh*DV + 16*dt + ln)*NTOK + mload);
        acc[dt] = __builtin_amdgcn_mfma_f32_16x16x32_f16(vf, pf, acc[dt], 0, 0, 0);
      }
    }
  }

  if (nvalid) {
    float li = 1.0f / L;
    uint16_t* Op = a2 + (size_t)bh * DV * NTOK;   // [b][h*128+d][n]
    #pragma unroll
    for (int dt = 0; dt < 8; ++dt)
      #pragma unroll
      for (int r = 0; r < 4; ++r) {
        int d = 16*dt + 4*lg + r;
        Op[(size_t)d * NTOK + n] = f2h(hswish(acc[dt][r] * li));
      }
  }
}

// ---------------- K3: proj GEMM (fp16 in, fp32 compute) + BN + hardswish, fp32 out
// grid (13, 3, nb) block 256
__global__ __launch_bounds__(256) void proj_kernel(
    const uint16_t* __restrict__ a2, const float* __restrict__ w,
    const float* __restrict__ gw, const float* __restrict__ bw,
    const float* __restrict__ mw, const float* __restrict__ vw,
    float* __restrict__ out)
{
  const int b  = blockIdx.z;
  const int m0 = blockIdx.y * 128;
  const int n0 = blockIdx.x * 64;
  const uint16_t* A2 = a2 + (size_t)b * DHTOT * NTOK;
  float* O = out + (size_t)b * DIMC * NTOK;

  __shared__ float As[16][128];
  __shared__ float Bs[16][68];

  const int tid = threadIdx.x;
  const int tx = tid & 15;
  const int ty = tid >> 4;

  const int lmm = tid & 127;
  const int lkk = (tid >> 7) * 8;
  const int lbk = tid >> 4;
  const int lbn = (tid & 15) * 4;
  const bool bvalid = (n0 + lbn) < NTOK;
  const float* wrow = w + (size_t)(m0 + lmm) * DHTOT;

  float acc[8][4];
  #pragma unroll
  for (int i = 0; i < 8; ++i)
    #pragma unroll
    for (int j = 0; j < 4; ++j) acc[i][j] = 0.f;

  for (int k0 = 0; k0 < DHTOT; k0 += 16) {
    float4 a0 = *reinterpret_cast<const float4*>(wrow + k0 + lkk);
    float4 a1 = *reinterpret_cast<const float4*>(wrow + k0 + lkk + 4);
    float4 b4 = make_float4(0.f, 0.f, 0.f, 0.f);
    if (bvalid)
      b4 = load_h4(A2 + (size_t)(k0 + lbk) * NTOK + n0 + lbn);
    __syncthreads();
    As[lkk+0][lmm] = a0.x; As[lkk+1][lmm] = a0.y; As[lkk+2][lmm] = a0.z; As[lkk+3][lmm] = a0.w;
    As[lkk+4][lmm] = a1.x; As[lkk+5][lmm] = a1.y; As[lkk+6][lmm] = a1.z; As[lkk+7][lmm] = a1.w;
    *reinterpret_cast<float4*>(&Bs[lbk][lbn]) = b4;
    __syncthreads();
    #pragma unroll
    for (int k = 0; k < 16; ++k) {
      float4 av0 = *reinterpret_cast<const float4*>(&As[k][ty*8]);
      float4 av1 = *reinterpret_cast<const float4*>(&As[k][ty*8+4]);
      float4 bv  = *reinterpret_cast<const float4*>(&Bs[k][tx*4]);
      float a[8] = {av0.x, av0.y, av0.z, av0.w, av1.x, av1.y, av1.z, av1.w};
      float bb[4] = {bv.x, bv.y, bv.z, bv.w};
      #pragma unroll
      for (int i = 0; i < 8; ++i)
        #pragma unroll
        for (int j = 0; j < 4; ++j) acc[i][j] += a[i] * bb[j];
    }
  }

  if (n0 + tx*4 < NTOK) {
    #pragma unroll
    for (int i = 0; i < 8; ++i) {
      int o = m0 + ty*8 + i;
      float sc = gw[o] * rsqrtf(vw[o] + BNEPS);
      float sh = bw[o] - mw[o] * sc;
      float4 r;
      r.x = hswish(acc[i][0]*sc + sh);
      r.y = hswish(acc[i][1]*sc + sh);
      r.z = hswish(acc[i][2]*sc + sh);
      r.w = hswish(acc[i][3]*sc + sh);
      *reinterpret_cast<float4*>(O + (size_t)o * NTOK + n0 + tx*4) = r;
    }
  }
}

extern "C" void kernel_launch(void* const* d_in, const int* in_sizes, int n_in,
                              void* d_out, int out_size, void* d_ws, size_t ws_size,
                              hipStream_t stream)
{
  const float* x  = (const float*)d_in[0];
  const float* qw = (const float*)d_in[1];
  const float* qg = (const float*)d_in[2];
  const float* qb_ = (const float*)d_in[3];
  const float* qm = (const float*)d_in[4];
  const float* qv = (const float*)d_in[5];
  const float* ab = (const float*)d_in[6];
  const float* pw = (const float*)d_in[7];
  const float* pg = (const float*)d_in[8];
  const float* pb = (const float*)d_in[9];
  const float* pm = (const float*)d_in[10];
  const float* pv = (const float*)d_in[11];
  float* out = (float*)d_out;

  const size_t QK_PER_B = (size_t)8 * NTOK * KD;    // 200704 elems
  const size_t V_PER_B  = (size_t)8 * DV * NTOK;    // 802816 elems
  const size_t A2_PER_B = (size_t)DHTOT * NTOK;     // 802816 elems
  const size_t per_b_bytes = (2*QK_PER_B + V_PER_B + A2_PER_B) * sizeof(uint16_t);

  int nb = (int)(ws_size / per_b_bytes);
  if (nb > BATCH) nb = BATCH;
  if (nb < 1) nb = 1;

  uint16_t* qbuf = (uint16_t*)d_ws;
  uint16_t* kbuf = qbuf + (size_t)nb * QK_PER_B;
  uint16_t* vbuf = kbuf + (size_t)nb * QK_PER_B;
  uint16_t* a2   = vbuf + (size_t)nb * V_PER_B;

  for (int b0 = 0; b0 < BATCH; b0 += nb) {
    int cb = BATCH - b0; if (cb > nb) cb = nb;
    const float* xb = x + (size_t)b0 * DIMC * NTOK;
    float* ob = out + (size_t)b0 * DIMC * NTOK;

    qkv_kernel<<<dim3(13, 12, cb), 256, 0, stream>>>(xb, qw, qg, qb_, qm, qv,
                                                     qbuf, kbuf, vbuf);
    attn_kernel<<<dim3(13, cb * 8), 256, 0, stream>>>(qbuf, kbuf, vbuf, ab, a2);
    proj_kernel<<<dim3(13, 3, cb), 256, 0, stream>>>(a2, pw, pg, pb, pm, pv, ob);
  }
}

// Round 3
// 573.815 us; speedup vs baseline: 8.9172x; 1.8413x over previous
//
#include <hip/hip_runtime.h>
#include <cstdint>

constexpr int BATCH = 32;
constexpr int DIMC  = 384;
constexpr int NTOK  = 784;
constexpr int KD    = 32;
constexpr int DV    = 128;
constexpr int PERH  = 192;
constexpr int HQKV  = 1536;
constexpr int DHTOT = 1024;
constexpr float BNEPS  = 1e-5f;
constexpr float QSCALE = 0.17677669529663687f;  // 1/sqrt(32)
constexpr float LOG2E  = 1.4426950408889634f;

#define DEVFN static __device__ __forceinline__

using f16x8 = __attribute__((ext_vector_type(8))) _Float16;
using f32x4 = __attribute__((ext_vector_type(4))) float;

DEVFN float hswish(float x) {
  float t = fminf(fmaxf(x + 3.0f, 0.0f), 6.0f);
  return x * t * (1.0f / 6.0f);
}
DEVFN uint16_t f2h(float f) { return __builtin_bit_cast(uint16_t, (_Float16)f); }

DEVFN void gload16(const void* g, void* l) {
  __builtin_amdgcn_global_load_lds(
      (const __attribute__((address_space(1))) void*)g,
      (__attribute__((address_space(3))) void*)l, 16, 0, 0);
}

// ---------------- P0a: weights fp32 -> fp16 (same layout)
__global__ __launch_bounds__(256) void convert_w(
    const float* __restrict__ qw, const float* __restrict__ pw,
    uint16_t* __restrict__ qwh, uint16_t* __restrict__ pwh)
{
  constexpr int QW4 = (HQKV * DIMC) / 4;    // 147456
  constexpr int PW4 = (DIMC * DHTOT) / 4;   // 98304
  int idx = blockIdx.x * 256 + threadIdx.x;
  if (idx < QW4) {
    float4 v = reinterpret_cast<const float4*>(qw)[idx];
    uint2 p;
    p.x = (uint32_t)f2h(v.x) | ((uint32_t)f2h(v.y) << 16);
    p.y = (uint32_t)f2h(v.z) | ((uint32_t)f2h(v.w) << 16);
    reinterpret_cast<uint2*>(qwh)[idx] = p;
  } else if (idx < QW4 + PW4) {
    int i2 = idx - QW4;
    float4 v = reinterpret_cast<const float4*>(pw)[i2];
    uint2 p;
    p.x = (uint32_t)f2h(v.x) | ((uint32_t)f2h(v.y) << 16);
    p.y = (uint32_t)f2h(v.z) | ((uint32_t)f2h(v.w) << 16);
    reinterpret_cast<uint2*>(pwh)[i2] = p;
  }
}

// ---------------- P0b: x [b][384][784] fp32 -> xT [b][784][384] fp16
// grid (25, 12, nb) block 256
__global__ __launch_bounds__(256) void transpose_x(
    const float* __restrict__ x, uint16_t* __restrict__ xT)
{
  const int b = blockIdx.z, n0 = blockIdx.x * 32, c0 = blockIdx.y * 32;
  __shared__ float t[32][33];
  const int tx = threadIdx.x & 31, ty = threadIdx.x >> 5;
  const float* xb = x + (size_t)b * DIMC * NTOK;
  #pragma unroll
  for (int k = 0; k < 4; ++k) {
    int c = c0 + ty + 8*k;
    int n = n0 + tx;
    t[ty + 8*k][tx] = (n < NTOK) ? xb[(size_t)c * NTOK + n] : 0.f;
  }
  __syncthreads();
  uint16_t* xTb = xT + (size_t)b * NTOK * DIMC;
  #pragma unroll
  for (int k = 0; k < 4; ++k) {
    int n = n0 + ty + 8*k;
    if (n < NTOK) xTb[(size_t)n * DIMC + c0 + tx] = f2h(t[tx][ty + 8*k]);
  }
}

// ---------------- K1: QKV MFMA GEMM. C[o][n] = sum_c W[o][c] xT[n][c].
// 128x64 tile, 4 waves 2x2, BK=64, double-buffered LDS + global_load_lds.
// Outputs: Q,K [bh][n][32] fp16 (scaled q), V [bh][128][n] fp16.
// grid (13, 12, nb) block 256
__global__ __launch_bounds__(256) void qkv_gemm(
    const uint16_t* __restrict__ wh, const uint16_t* __restrict__ xT,
    const float* __restrict__ gw, const float* __restrict__ bw,
    const float* __restrict__ mw, const float* __restrict__ vw,
    uint16_t* __restrict__ qb, uint16_t* __restrict__ kb, uint16_t* __restrict__ vb)
{
  const int b  = blockIdx.z;
  const int m0 = blockIdx.y * 128;
  const int n0 = blockIdx.x * 64;
  __shared__ __align__(16) uint16_t As[2][128*64];
  __shared__ __align__(16) uint16_t Bs[2][64*64];

  const int tid = threadIdx.x;
  const int w = tid >> 6, l = tid & 63, lg = l >> 4, ln = l & 15;
  const int wr = w >> 1, wc = w & 1;
  const int wbase = tid & 192;
  const uint16_t* xb = xT + (size_t)b * NTOK * DIMC;

  f32x4 acc[4][2];
  #pragma unroll
  for (int mi = 0; mi < 4; ++mi)
    #pragma unroll
    for (int ni = 0; ni < 2; ++ni) acc[mi][ni] = (f32x4){0.f,0.f,0.f,0.f};

  auto stage = [&](int buf, int k0) {
    #pragma unroll
    for (int j = 0; j < 4; ++j) {           // A: 128 rows x 8 slots
      int s = j*256 + tid;
      int row = s >> 3, sl = s & 7;
      int srck = k0 + 8 * (sl ^ (row & 7));
      gload16(wh + (size_t)(m0 + row) * DIMC + srck,
              &As[buf][(j*256 + wbase) * 8]);
    }
    #pragma unroll
    for (int j = 0; j < 2; ++j) {           // B: 64 rows x 8 slots
      int s = j*256 + tid;
      int row = s >> 3, sl = s & 7;
      int nrow = n0 + row; if (nrow > NTOK-1) nrow = NTOK-1;
      int srck = k0 + 8 * (sl ^ (row & 7));
      gload16(xb + (size_t)nrow * DIMC + srck,
              &Bs[buf][(j*256 + wbase) * 8]);
    }
  };

  stage(0, 0);
  int cur = 0;
  for (int k0 = 0; k0 < DIMC; k0 += 64) {
    __syncthreads();                         // buf[cur] staged; prev reads done
    if (k0 + 64 < DIMC) stage(cur ^ 1, k0 + 64);
    #pragma unroll
    for (int kk = 0; kk < 2; ++kk) {
      f16x8 af[4], bf[2];
      #pragma unroll
      for (int mi = 0; mi < 4; ++mi) {
        int row = 64*wr + 16*mi + ln;
        int slot = (4*kk + lg) ^ (row & 7);
        af[mi] = *reinterpret_cast<const f16x8*>(&As[cur][row*64 + slot*8]);
      }
      #pragma unroll
      for (int ni = 0; ni < 2; ++ni) {
        int row = 32*wc + 16*ni + ln;
        int slot = (4*kk + lg) ^ (row & 7);
        bf[ni] = *reinterpret_cast<const f16x8*>(&Bs[cur][row*64 + slot*8]);
      }
      #pragma unroll
      for (int mi = 0; mi < 4; ++mi)
        #pragma unroll
        for (int ni = 0; ni < 2; ++ni)
          acc[mi][ni] = __builtin_amdgcn_mfma_f32_16x16x32_f16(
              af[mi], bf[ni], acc[mi][ni], 0, 0, 0);
    }
    cur ^= 1;
  }

  // epilogue: D col = ln -> n, row = 4lg+r -> o
  #pragma unroll
  for (int mi = 0; mi < 4; ++mi) {
    const int ob = m0 + 64*wr + 16*mi;       // 16-aligned, one segment type
    const int h  = ob / PERH;
    const int r0 = ob - h * PERH;
    const int bh = b*8 + h;
    float sc[4], sh[4];
    #pragma unroll
    for (int r = 0; r < 4; ++r) {
      int o = ob + 4*lg + r;
      float s = gw[o] * rsqrtf(vw[o] + BNEPS);
      sc[r] = s; sh[r] = bw[o] - mw[o]*s;
    }
    #pragma unroll
    for (int ni = 0; ni < 2; ++ni) {
      int n = n0 + 32*wc + 16*ni + ln;
      if (n >= NTOK) continue;
      float v4[4];
      #pragma unroll
      for (int r = 0; r < 4; ++r) v4[r] = hswish(acc[mi][ni][r]*sc[r] + sh[r]);
      if (r0 < 2*KD) {
        if (r0 < KD) {
          #pragma unroll
          for (int r = 0; r < 4; ++r) v4[r] *= QSCALE;
        }
        uint16_t* base = (r0 < KD) ? qb : kb;
        int dd = (r0 & 16) + 4*lg;
        uint2 p;
        p.x = (uint32_t)f2h(v4[0]) | ((uint32_t)f2h(v4[1]) << 16);
        p.y = (uint32_t)f2h(v4[2]) | ((uint32_t)f2h(v4[3]) << 16);
        *reinterpret_cast<uint2*>(base + ((size_t)bh*NTOK + n)*KD + dd) = p;
      } else {
        int dv = r0 - 2*KD + 4*lg;
        #pragma unroll
        for (int r = 0; r < 4; ++r)
          vb[((size_t)bh*DV + dv + r)*NTOK + n] = f2h(v4[r]);
      }
    }
  }
}

// ---------------- K2: MFMA flash attention -> O[n][d] (a2T [b][n][1024])
// grid (13, nb*8) block 256
__global__ __launch_bounds__(256) void attn_kernel(
    const uint16_t* __restrict__ Qb, const uint16_t* __restrict__ Kb,
    const uint16_t* __restrict__ Vb, const float* __restrict__ biases,
    uint16_t* __restrict__ a2T)
{
  const int bh = blockIdx.y;
  const int b_ = bh >> 3;
  const int h  = bh & 7;
  const int n0 = blockIdx.x * 64;

  __shared__ float biasl[NTOK];
  __shared__ __align__(16) uint16_t plds[4][16][72];

  const int tid = threadIdx.x;
  const int w   = tid >> 6;
  const int l   = tid & 63;
  const int lg  = l >> 4;
  const int ln  = l & 15;

  for (int i = tid; i < NTOK; i += 256) biasl[i] = biases[(size_t)h*NTOK + i];

  const int nraw = n0 + 16*w + ln;
  const int n  = (nraw < NTOK) ? nraw : (NTOK-1);
  const int ri = (n * 2341) >> 16;
  const int rj = n - ri*28;

  const f16x8 qf = *reinterpret_cast<const f16x8*>(Qb + ((size_t)bh*NTOK + n)*KD + 8*lg);

  float M = -1e30f, L = 0.f;
  f32x4 acc[8];
  #pragma unroll
  for (int dt = 0; dt < 8; ++dt) acc[dt] = (f32x4){0.f,0.f,0.f,0.f};

  __syncthreads();

  for (int mb = 0; mb < NTOK; mb += 64) {
    const int rem   = (NTOK - mb) >> 4;
    const int ntile = rem < 4 ? rem : 4;

    float p[16];
    #pragma unroll
    for (int i = 0; i < 16; ++i) p[i] = -1e30f;

    #pragma unroll
    for (int t = 0; t < 4; ++t) {
      if (t < ntile) {
        f16x8 kf = *reinterpret_cast<const f16x8*>(
            Kb + ((size_t)bh*NTOK + mb + 16*t + ln)*KD + 8*lg);
        f32x4 st = __builtin_amdgcn_mfma_f32_16x16x32_f16(
            kf, qf, (f32x4){0.f,0.f,0.f,0.f}, 0, 0, 0);
        #pragma unroll
        for (int r = 0; r < 4; ++r) {
          int m  = mb + 16*t + 4*lg + r;
          int im = (m * 2341) >> 16;
          int jm = m - im*28;
          int di = ri - im; di = di < 0 ? -di : di;
          int dj = rj - jm; dj = dj < 0 ? -dj : dj;
          p[4*t + r] = st[r] + biasl[di*28 + dj];
        }
      }
    }

    float mx = p[0];
    #pragma unroll
    for (int i = 1; i < 16; ++i) mx = fmaxf(mx, p[i]);
    mx = fmaxf(mx, __shfl_xor(mx, 16));
    mx = fmaxf(mx, __shfl_xor(mx, 32));

    float Mn = fmaxf(M, mx);
    float al = exp2f((M - Mn) * LOG2E);
    float sum = 0.f;
    #pragma unroll
    for (int i = 0; i < 16; ++i) { p[i] = exp2f((p[i] - Mn) * LOG2E); sum += p[i]; }
    sum += __shfl_xor(sum, 16);
    sum += __shfl_xor(sum, 32);
    L = L * al + sum;
    M = Mn;

    float al4[4];
    #pragma unroll
    for (int r = 0; r < 4; ++r) al4[r] = __shfl(al, 20*lg + r);  // al of row 4lg+r
    #pragma unroll
    for (int dt = 0; dt < 8; ++dt) {
      acc[dt][0] *= al4[0]; acc[dt][1] *= al4[1];
      acc[dt][2] *= al4[2]; acc[dt][3] *= al4[3];
    }

    #pragma unroll
    for (int t = 0; t < 4; ++t) {
      uint2 pk;
      pk.x = (uint32_t)f2h(p[4*t+0]) | ((uint32_t)f2h(p[4*t+1]) << 16);
      pk.y = (uint32_t)f2h(p[4*t+2]) | ((uint32_t)f2h(p[4*t+3]) << 16);
      *reinterpret_cast<uint2*>(&plds[w][ln][16*t + 4*lg]) = pk;
    }
    __syncthreads();

    #pragma unroll
    for (int ks = 0; ks < 2; ++ks) {
      f16x8 pf = *reinterpret_cast<const f16x8*>(&plds[w][ln][32*ks + 8*lg]);
      int mload = mb + 32*ks + 8*lg;
      if (mload > NTOK-8) mload = NTOK-8;
      #pragma unroll
      for (int dt = 0; dt < 8; ++dt) {
        f16x8 vf = *reinterpret_cast<const f16x8*>(
            Vb + ((size_t)bh*DV + 16*dt + ln)*NTOK + mload);
        acc[dt] = __builtin_amdgcn_mfma_f32_16x16x32_f16(pf, vf, acc[dt], 0, 0, 0);
      }
    }
  }

  float li = 1.0f / L;
  float li4[4];
  #pragma unroll
  for (int r = 0; r < 4; ++r) li4[r] = __shfl(li, 20*lg + r);
  #pragma unroll
  for (int r = 0; r < 4; ++r) {
    int n_row = n0 + 16*w + 4*lg + r;
    if (n_row < NTOK) {
      #pragma unroll
      for (int dt = 0; dt < 8; ++dt)
        a2T[((size_t)b_*NTOK + n_row)*DHTOT + h*DV + 16*dt + ln] =
            f2h(hswish(acc[dt][r] * li4[r]));
    }
  }
}

// ---------------- K3: proj MFMA GEMM. out[o][n] = sum_d Wp[o][d] a2T[n][d].
// grid (13, 3, nb) block 256
__global__ __launch_bounds__(256) void proj_gemm(
    const uint16_t* __restrict__ wh, const uint16_t* __restrict__ a2T,
    const float* __restrict__ gw, const float* __restrict__ bw,
    const float* __restrict__ mw, const float* __restrict__ vw,
    float* __restrict__ out)
{
  const int b  = blockIdx.z;
  const int m0 = blockIdx.y * 128;
  const int n0 = blockIdx.x * 64;
  __shared__ __align__(16) uint16_t As[2][128*64];
  __shared__ __align__(16) uint16_t Bs[2][64*64];

  const int tid = threadIdx.x;
  const int w = tid >> 6, l = tid & 63, lg = l >> 4, ln = l & 15;
  const int wr = w >> 1, wc = w & 1;
  const int wbase = tid & 192;
  const uint16_t* ab = a2T + (size_t)b * NTOK * DHTOT;

  f32x4 acc[4][2];
  #pragma unroll
  for (int mi = 0; mi < 4; ++mi)
    #pragma unroll
    for (int ni = 0; ni < 2; ++ni) acc[mi][ni] = (f32x4){0.f,0.f,0.f,0.f};

  auto stage = [&](int buf, int k0) {
    #pragma unroll
    for (int j = 0; j < 4; ++j) {
      int s = j*256 + tid;
      int row = s >> 3, sl = s & 7;
      int srck = k0 + 8 * (sl ^ (row & 7));
      gload16(wh + (size_t)(m0 + row) * DHTOT + srck,
              &As[buf][(j*256 + wbase) * 8]);
    }
    #pragma unroll
    for (int j = 0; j < 2; ++j) {
      int s = j*256 + tid;
      int row = s >> 3, sl = s & 7;
      int nrow = n0 + row; if (nrow > NTOK-1) nrow = NTOK-1;
      int srck = k0 + 8 * (sl ^ (row & 7));
      gload16(ab + (size_t)nrow * DHTOT + srck,
              &Bs[buf][(j*256 + wbase) * 8]);
    }
  };

  stage(0, 0);
  int cur = 0;
  for (int k0 = 0; k0 < DHTOT; k0 += 64) {
    __syncthreads();
    if (k0 + 64 < DHTOT) stage(cur ^ 1, k0 + 64);
    #pragma unroll
    for (int kk = 0; kk < 2; ++kk) {
      f16x8 af[4], bf[2];
      #pragma unroll
      for (int mi = 0; mi < 4; ++mi) {
        int row = 64*wr + 16*mi + ln;
        int slot = (4*kk + lg) ^ (row & 7);
        af[mi] = *reinterpret_cast<const f16x8*>(&As[cur][row*64 + slot*8]);
      }
      #pragma unroll
      for (int ni = 0; ni < 2; ++ni) {
        int row = 32*wc + 16*ni + ln;
        int slot = (4*kk + lg) ^ (row & 7);
        bf[ni] = *reinterpret_cast<const f16x8*>(&Bs[cur][row*64 + slot*8]);
      }
      #pragma unroll
      for (int mi = 0; mi < 4; ++mi)
        #pragma unroll
        for (int ni = 0; ni < 2; ++ni)
          acc[mi][ni] = __builtin_amdgcn_mfma_f32_16x16x32_f16(
              af[mi], bf[ni], acc[mi][ni], 0, 0, 0);
    }
    cur ^= 1;
  }

  #pragma unroll
  for (int mi = 0; mi < 4; ++mi) {
    float sc[4], sh[4];
    #pragma unroll
    for (int r = 0; r < 4; ++r) {
      int o = m0 + 64*wr + 16*mi + 4*lg + r;
      float s = gw[o] * rsqrtf(vw[o] + BNEPS);
      sc[r] = s; sh[r] = bw[o] - mw[o]*s;
    }
    #pragma unroll
    for (int ni = 0; ni < 2; ++ni) {
      int n = n0 + 32*wc + 16*ni + ln;
      if (n >= NTOK) continue;
      #pragma unroll
      for (int r = 0; r < 4; ++r) {
        int o = m0 + 64*wr + 16*mi + 4*lg + r;
        out[((size_t)b*DIMC + o)*NTOK + n] = hswish(acc[mi][ni][r]*sc[r] + sh[r]);
      }
    }
  }
}

extern "C" void kernel_launch(void* const* d_in, const int* in_sizes, int n_in,
                              void* d_out, int out_size, void* d_ws, size_t ws_size,
                              hipStream_t stream)
{
  const float* x  = (const float*)d_in[0];
  const float* qw = (const float*)d_in[1];
  const float* qg = (const float*)d_in[2];
  const float* qb_ = (const float*)d_in[3];
  const float* qm = (const float*)d_in[4];
  const float* qv = (const float*)d_in[5];
  const float* ab = (const float*)d_in[6];
  const float* pw = (const float*)d_in[7];
  const float* pg = (const float*)d_in[8];
  const float* pb = (const float*)d_in[9];
  const float* pm = (const float*)d_in[10];
  const float* pv = (const float*)d_in[11];
  float* out = (float*)d_out;

  uint16_t* qwh = (uint16_t*)d_ws;
  uint16_t* pwh = qwh + (size_t)HQKV * DIMC;
  uint16_t* dyn = pwh + (size_t)DIMC * DHTOT;
  const size_t fixed_bytes = ((size_t)HQKV*DIMC + (size_t)DIMC*DHTOT) * 2;

  const size_t XT_B = (size_t)NTOK * DIMC;      // 301056
  const size_t QK_B = (size_t)8 * NTOK * KD;    // 200704
  const size_t V_B  = (size_t)8 * DV * NTOK;    // 802816
  const size_t A2_B = (size_t)NTOK * DHTOT;     // 802816
  const size_t PER_B = XT_B + 2*QK_B + V_B + A2_B;

  size_t avail = (ws_size > fixed_bytes) ? (ws_size - fixed_bytes) : 0;
  int nb = (int)(avail / (PER_B * 2));
  if (nb > BATCH) nb = BATCH;
  if (nb < 1) nb = 1;

  uint16_t* xTb  = dyn;
  uint16_t* qbuf = xTb  + (size_t)nb * XT_B;
  uint16_t* kbuf = qbuf + (size_t)nb * QK_B;
  uint16_t* vbuf = kbuf + (size_t)nb * QK_B;
  uint16_t* a2   = vbuf + (size_t)nb * V_B;

  convert_w<<<960, 256, 0, stream>>>(qw, pw, qwh, pwh);

  for (int b0 = 0; b0 < BATCH; b0 += nb) {
    int cb = BATCH - b0; if (cb > nb) cb = nb;
    const float* xb = x + (size_t)b0 * DIMC * NTOK;
    float* ob = out + (size_t)b0 * DIMC * NTOK;

    transpose_x<<<dim3(25, 12, cb), 256, 0, stream>>>(xb, xTb);
    qkv_gemm<<<dim3(13, 12, cb), 256, 0, stream>>>(qwh, xTb, qg, qb_, qm, qv,
                                                   qbuf, kbuf, vbuf);
    attn_kernel<<<dim3(13, cb * 8), 256, 0, stream>>>(qbuf, kbuf, vbuf, ab, a2);
    proj_gemm<<<dim3(13, 3, cb), 256, 0, stream>>>(pwh, a2, pg, pb, pm, pv, ob);
  }
}

// Round 4
// 424.273 us; speedup vs baseline: 12.0603x; 1.3525x over previous
//
#include <hip/hip_runtime.h>
#include <cstdint>

constexpr int BATCH = 32;
constexpr int DIMC  = 384;
constexpr int NTOK  = 784;
constexpr int KD    = 32;
constexpr int DV    = 128;
constexpr int PERH  = 192;
constexpr int HQKV  = 1536;
constexpr int DHTOT = 1024;
constexpr float BNEPS  = 1e-5f;
constexpr float QSCALE = 0.17677669529663687f;  // 1/sqrt(32)
constexpr float LOG2E  = 1.4426950408889634f;

#define DEVFN static __device__ __forceinline__

using f16x8 = __attribute__((ext_vector_type(8))) _Float16;
using f32x4 = __attribute__((ext_vector_type(4))) float;

DEVFN float hswish(float x) {
  float t = fminf(fmaxf(x + 3.0f, 0.0f), 6.0f);
  return x * t * (1.0f / 6.0f);
}
DEVFN uint16_t f2h(float f) { return __builtin_bit_cast(uint16_t, (_Float16)f); }

DEVFN void gload16(const void* g, void* l) {
  __builtin_amdgcn_global_load_lds(
      (const __attribute__((address_space(1))) void*)g,
      (__attribute__((address_space(3))) void*)l, 16, 0, 0);
}

// ---------------- P0a: weights fp32 -> fp16 (same layout)
__global__ __launch_bounds__(256) void convert_w(
    const float* __restrict__ qw, const float* __restrict__ pw,
    uint16_t* __restrict__ qwh, uint16_t* __restrict__ pwh)
{
  constexpr int QW4 = (HQKV * DIMC) / 4;    // 147456
  constexpr int PW4 = (DIMC * DHTOT) / 4;   // 98304
  int idx = blockIdx.x * 256 + threadIdx.x;
  if (idx < QW4) {
    float4 v = reinterpret_cast<const float4*>(qw)[idx];
    uint2 p;
    p.x = (uint32_t)f2h(v.x) | ((uint32_t)f2h(v.y) << 16);
    p.y = (uint32_t)f2h(v.z) | ((uint32_t)f2h(v.w) << 16);
    reinterpret_cast<uint2*>(qwh)[idx] = p;
  } else if (idx < QW4 + PW4) {
    int i2 = idx - QW4;
    float4 v = reinterpret_cast<const float4*>(pw)[i2];
    uint2 p;
    p.x = (uint32_t)f2h(v.x) | ((uint32_t)f2h(v.y) << 16);
    p.y = (uint32_t)f2h(v.z) | ((uint32_t)f2h(v.w) << 16);
    reinterpret_cast<uint2*>(pwh)[i2] = p;
  }
}

// ---------------- P0b: x [b][384][784] fp32 -> xT [b][784][384] fp16
// grid (25, 12, nb) block 256
__global__ __launch_bounds__(256) void transpose_x(
    const float* __restrict__ x, uint16_t* __restrict__ xT)
{
  const int b = blockIdx.z, n0 = blockIdx.x * 32, c0 = blockIdx.y * 32;
  __shared__ float t[32][33];
  const int tx = threadIdx.x & 31, ty = threadIdx.x >> 5;
  const float* xb = x + (size_t)b * DIMC * NTOK;
  #pragma unroll
  for (int k = 0; k < 4; ++k) {
    int c = c0 + ty + 8*k;
    int n = n0 + tx;
    t[ty + 8*k][tx] = (n < NTOK) ? xb[(size_t)c * NTOK + n] : 0.f;
  }
  __syncthreads();
  uint16_t* xTb = xT + (size_t)b * NTOK * DIMC;
  #pragma unroll
  for (int k = 0; k < 4; ++k) {
    int n = n0 + ty + 8*k;
    if (n < NTOK) xTb[(size_t)n * DIMC + c0 + tx] = f2h(t[tx][ty + 8*k]);
  }
}

// ---------------- K1: QKV MFMA GEMM. C[o][n] = sum_c W[o][c] xT[n][c].
// 128x64 tile, 4 waves 2x2, BK=64, double-buffered LDS + global_load_lds.
// Outputs: Q,K [bh][n][32] fp16 (scaled q), V [bh][128][n] fp16.
// grid (13, 12, nb) block 256
__global__ __launch_bounds__(256) void qkv_gemm(
    const uint16_t* __restrict__ wh, const uint16_t* __restrict__ xT,
    const float* __restrict__ gw, const float* __restrict__ bw,
    const float* __restrict__ mw, const float* __restrict__ vw,
    uint16_t* __restrict__ qb, uint16_t* __restrict__ kb, uint16_t* __restrict__ vb)
{
  const int b  = blockIdx.z;
  const int m0 = blockIdx.y * 128;
  const int n0 = blockIdx.x * 64;
  __shared__ __align__(16) uint16_t As[2][128*64];
  __shared__ __align__(16) uint16_t Bs[2][64*64];

  const int tid = threadIdx.x;
  const int w = tid >> 6, l = tid & 63, lg = l >> 4, ln = l & 15;
  const int wr = w >> 1, wc = w & 1;
  const int wbase = tid & 192;
  const uint16_t* xb = xT + (size_t)b * NTOK * DIMC;

  f32x4 acc[4][2];
  #pragma unroll
  for (int mi = 0; mi < 4; ++mi)
    #pragma unroll
    for (int ni = 0; ni < 2; ++ni) acc[mi][ni] = (f32x4){0.f,0.f,0.f,0.f};

  auto stage = [&](int buf, int k0) {
    #pragma unroll
    for (int j = 0; j < 4; ++j) {           // A: 128 rows x 8 slots
      int s = j*256 + tid;
      int row = s >> 3, sl = s & 7;
      int srck = k0 + 8 * (sl ^ (row & 7));
      gload16(wh + (size_t)(m0 + row) * DIMC + srck,
              &As[buf][(j*256 + wbase) * 8]);
    }
    #pragma unroll
    for (int j = 0; j < 2; ++j) {           // B: 64 rows x 8 slots
      int s = j*256 + tid;
      int row = s >> 3, sl = s & 7;
      int nrow = n0 + row; if (nrow > NTOK-1) nrow = NTOK-1;
      int srck = k0 + 8 * (sl ^ (row & 7));
      gload16(xb + (size_t)nrow * DIMC + srck,
              &Bs[buf][(j*256 + wbase) * 8]);
    }
  };

  stage(0, 0);
  int cur = 0;
  for (int k0 = 0; k0 < DIMC; k0 += 64) {
    __syncthreads();                         // buf[cur] staged; prev reads done
    if (k0 + 64 < DIMC) stage(cur ^ 1, k0 + 64);
    #pragma unroll
    for (int kk = 0; kk < 2; ++kk) {
      f16x8 af[4], bf[2];
      #pragma unroll
      for (int mi = 0; mi < 4; ++mi) {
        int row = 64*wr + 16*mi + ln;
        int slot = (4*kk + lg) ^ (row & 7);
        af[mi] = *reinterpret_cast<const f16x8*>(&As[cur][row*64 + slot*8]);
      }
      #pragma unroll
      for (int ni = 0; ni < 2; ++ni) {
        int row = 32*wc + 16*ni + ln;
        int slot = (4*kk + lg) ^ (row & 7);
        bf[ni] = *reinterpret_cast<const f16x8*>(&Bs[cur][row*64 + slot*8]);
      }
      #pragma unroll
      for (int mi = 0; mi < 4; ++mi)
        #pragma unroll
        for (int ni = 0; ni < 2; ++ni)
          acc[mi][ni] = __builtin_amdgcn_mfma_f32_16x16x32_f16(
              af[mi], bf[ni], acc[mi][ni], 0, 0, 0);
    }
    cur ^= 1;
  }

  // epilogue: D col = ln -> n, row = 4lg+r -> o
  #pragma unroll
  for (int mi = 0; mi < 4; ++mi) {
    const int ob = m0 + 64*wr + 16*mi;       // 16-aligned, one segment type
    const int h  = ob / PERH;
    const int r0 = ob - h * PERH;
    const int bh = b*8 + h;
    float sc[4], sh[4];
    #pragma unroll
    for (int r = 0; r < 4; ++r) {
      int o = ob + 4*lg + r;
      float s = gw[o] * rsqrtf(vw[o] + BNEPS);
      sc[r] = s; sh[r] = bw[o] - mw[o]*s;
    }
    #pragma unroll
    for (int ni = 0; ni < 2; ++ni) {
      int n = n0 + 32*wc + 16*ni + ln;
      if (n >= NTOK) continue;
      float v4[4];
      #pragma unroll
      for (int r = 0; r < 4; ++r) v4[r] = hswish(acc[mi][ni][r]*sc[r] + sh[r]);
      if (r0 < 2*KD) {
        if (r0 < KD) {
          #pragma unroll
          for (int r = 0; r < 4; ++r) v4[r] *= QSCALE;
        }
        uint16_t* base = (r0 < KD) ? qb : kb;
        int dd = (r0 & 16) + 4*lg;
        uint2 p;
        p.x = (uint32_t)f2h(v4[0]) | ((uint32_t)f2h(v4[1]) << 16);
        p.y = (uint32_t)f2h(v4[2]) | ((uint32_t)f2h(v4[3]) << 16);
        *reinterpret_cast<uint2*>(base + ((size_t)bh*NTOK + n)*KD + dd) = p;
      } else {
        int dv = r0 - 2*KD + 4*lg;
        #pragma unroll
        for (int r = 0; r < 4; ++r)
          vb[((size_t)bh*DV + dv + r)*NTOK + n] = f2h(v4[r]);
      }
    }
  }
}

// ---------------- K2: MFMA flash attention -> O[n][d] (a2T [b][n][1024])
// 2 waves/block, 16 q-rows/wave, NO barrier in chunk loop (plds wave-private).
// grid (25, nb*8) block 128
__global__ __launch_bounds__(128) void attn_kernel(
    const uint16_t* __restrict__ Qb, const uint16_t* __restrict__ Kb,
    const uint16_t* __restrict__ Vb, const float* __restrict__ biases,
    uint16_t* __restrict__ a2T)
{
  const int bh = blockIdx.y;
  const int b_ = bh >> 3;
  const int h  = bh & 7;
  const int n0 = blockIdx.x * 32;

  __shared__ float biasl[NTOK];
  __shared__ __align__(16) uint16_t plds[2][16][72];

  const int tid = threadIdx.x;
  const int w   = tid >> 6;
  const int l   = tid & 63;
  const int lg  = l >> 4;
  const int ln  = l & 15;

  for (int i = tid; i < NTOK; i += 128) biasl[i] = biases[(size_t)h*NTOK + i];

  const int nraw = n0 + 16*w + ln;
  const int n  = (nraw < NTOK) ? nraw : (NTOK-1);
  const int ri = (n * 2341) >> 16;
  const int rj = n - ri*28;

  const f16x8 qf = *reinterpret_cast<const f16x8*>(Qb + ((size_t)bh*NTOK + n)*KD + 8*lg);

  float M = -1e30f, L = 0.f;
  f32x4 acc[8];
  #pragma unroll
  for (int dt = 0; dt < 8; ++dt) acc[dt] = (f32x4){0.f,0.f,0.f,0.f};

  __syncthreads();    // biasl ready (only barrier in kernel)

  for (int mb = 0; mb < NTOK; mb += 64) {
    const int rem   = (NTOK - mb) >> 4;
    const int ntile = rem < 4 ? rem : 4;

    float p[16];
    #pragma unroll
    for (int i = 0; i < 16; ++i) p[i] = -1e30f;

    #pragma unroll
    for (int t = 0; t < 4; ++t) {
      if (t < ntile) {
        f16x8 kf = *reinterpret_cast<const f16x8*>(
            Kb + ((size_t)bh*NTOK + mb + 16*t + ln)*KD + 8*lg);
        f32x4 st = __builtin_amdgcn_mfma_f32_16x16x32_f16(
            kf, qf, (f32x4){0.f,0.f,0.f,0.f}, 0, 0, 0);
        #pragma unroll
        for (int r = 0; r < 4; ++r) {
          int m  = mb + 16*t + 4*lg + r;
          int im = (m * 2341) >> 16;
          int jm = m - im*28;
          int di = ri - im; di = di < 0 ? -di : di;
          int dj = rj - jm; dj = dj < 0 ? -dj : dj;
          p[4*t + r] = st[r] + biasl[di*28 + dj];
        }
      }
    }

    float mx = p[0];
    #pragma unroll
    for (int i = 1; i < 16; ++i) mx = fmaxf(mx, p[i]);
    mx = fmaxf(mx, __shfl_xor(mx, 16));
    mx = fmaxf(mx, __shfl_xor(mx, 32));

    float Mn = fmaxf(M, mx);
    float al = exp2f((M - Mn) * LOG2E);
    float sum = 0.f;
    #pragma unroll
    for (int i = 0; i < 16; ++i) { p[i] = exp2f((p[i] - Mn) * LOG2E); sum += p[i]; }
    sum += __shfl_xor(sum, 16);
    sum += __shfl_xor(sum, 32);
    L = L * al + sum;
    M = Mn;

    float al4[4];
    #pragma unroll
    for (int r = 0; r < 4; ++r) al4[r] = __shfl(al, 20*lg + r);
    #pragma unroll
    for (int dt = 0; dt < 8; ++dt) {
      acc[dt][0] *= al4[0]; acc[dt][1] *= al4[1];
      acc[dt][2] *= al4[2]; acc[dt][3] *= al4[3];
    }

    #pragma unroll
    for (int t = 0; t < 4; ++t) {
      uint2 pk;
      pk.x = (uint32_t)f2h(p[4*t+0]) | ((uint32_t)f2h(p[4*t+1]) << 16);
      pk.y = (uint32_t)f2h(p[4*t+2]) | ((uint32_t)f2h(p[4*t+3]) << 16);
      *reinterpret_cast<uint2*>(&plds[w][ln][16*t + 4*lg]) = pk;
    }
    // no barrier: plds is wave-private; compiler orders intra-wave LDS RAW.

    #pragma unroll
    for (int ks = 0; ks < 2; ++ks) {
      f16x8 pf = *reinterpret_cast<const f16x8*>(&plds[w][ln][32*ks + 8*lg]);
      int mload = mb + 32*ks + 8*lg;
      if (mload > NTOK-8) mload = NTOK-8;
      f16x8 vf[8];
      #pragma unroll
      for (int dt = 0; dt < 8; ++dt)
        vf[dt] = *reinterpret_cast<const f16x8*>(
            Vb + ((size_t)bh*DV + 16*dt + ln)*NTOK + mload);
      __builtin_amdgcn_s_setprio(1);
      #pragma unroll
      for (int dt = 0; dt < 8; ++dt)
        acc[dt] = __builtin_amdgcn_mfma_f32_16x16x32_f16(pf, vf[dt], acc[dt], 0, 0, 0);
      __builtin_amdgcn_s_setprio(0);
    }
  }

  float li = 1.0f / L;
  float li4[4];
  #pragma unroll
  for (int r = 0; r < 4; ++r) li4[r] = __shfl(li, 20*lg + r);
  #pragma unroll
  for (int r = 0; r < 4; ++r) {
    int n_row = n0 + 16*w + 4*lg + r;
    if (n_row < NTOK) {
      #pragma unroll
      for (int dt = 0; dt < 8; ++dt)
        a2T[((size_t)b_*NTOK + n_row)*DHTOT + h*DV + 16*dt + ln] =
            f2h(hswish(acc[dt][r] * li4[r]));
    }
  }
}

// ---------------- K3: proj MFMA GEMM. out[o][n] = sum_d Wp[o][d] a2T[n][d].
// grid (13, 3, nb) block 256
__global__ __launch_bounds__(256) void proj_gemm(
    const uint16_t* __restrict__ wh, const uint16_t* __restrict__ a2T,
    const float* __restrict__ gw, const float* __restrict__ bw,
    const float* __restrict__ mw, const float* __restrict__ vw,
    float* __restrict__ out)
{
  const int b  = blockIdx.z;
  const int m0 = blockIdx.y * 128;
  const int n0 = blockIdx.x * 64;
  __shared__ __align__(16) uint16_t As[2][128*64];
  __shared__ __align__(16) uint16_t Bs[2][64*64];

  const int tid = threadIdx.x;
  const int w = tid >> 6, l = tid & 63, lg = l >> 4, ln = l & 15;
  const int wr = w >> 1, wc = w & 1;
  const int wbase = tid & 192;
  const uint16_t* ab = a2T + (size_t)b * NTOK * DHTOT;

  f32x4 acc[4][2];
  #pragma unroll
  for (int mi = 0; mi < 4; ++mi)
    #pragma unroll
    for (int ni = 0; ni < 2; ++ni) acc[mi][ni] = (f32x4){0.f,0.f,0.f,0.f};

  auto stage = [&](int buf, int k0) {
    #pragma unroll
    for (int j = 0; j < 4; ++j) {
      int s = j*256 + tid;
      int row = s >> 3, sl = s & 7;
      int srck = k0 + 8 * (sl ^ (row & 7));
      gload16(wh + (size_t)(m0 + row) * DHTOT + srck,
              &As[buf][(j*256 + wbase) * 8]);
    }
    #pragma unroll
    for (int j = 0; j < 2; ++j) {
      int s = j*256 + tid;
      int row = s >> 3, sl = s & 7;
      int nrow = n0 + row; if (nrow > NTOK-1) nrow = NTOK-1;
      int srck = k0 + 8 * (sl ^ (row & 7));
      gload16(ab + (size_t)nrow * DHTOT + srck,
              &Bs[buf][(j*256 + wbase) * 8]);
    }
  };

  stage(0, 0);
  int cur = 0;
  for (int k0 = 0; k0 < DHTOT; k0 += 64) {
    __syncthreads();
    if (k0 + 64 < DHTOT) stage(cur ^ 1, k0 + 64);
    #pragma unroll
    for (int kk = 0; kk < 2; ++kk) {
      f16x8 af[4], bf[2];
      #pragma unroll
      for (int mi = 0; mi < 4; ++mi) {
        int row = 64*wr + 16*mi + ln;
        int slot = (4*kk + lg) ^ (row & 7);
        af[mi] = *reinterpret_cast<const f16x8*>(&As[cur][row*64 + slot*8]);
      }
      #pragma unroll
      for (int ni = 0; ni < 2; ++ni) {
        int row = 32*wc + 16*ni + ln;
        int slot = (4*kk + lg) ^ (row & 7);
        bf[ni] = *reinterpret_cast<const f16x8*>(&Bs[cur][row*64 + slot*8]);
      }
      #pragma unroll
      for (int mi = 0; mi < 4; ++mi)
        #pragma unroll
        for (int ni = 0; ni < 2; ++ni)
          acc[mi][ni] = __builtin_amdgcn_mfma_f32_16x16x32_f16(
              af[mi], bf[ni], acc[mi][ni], 0, 0, 0);
    }
    cur ^= 1;
  }

  #pragma unroll
  for (int mi = 0; mi < 4; ++mi) {
    float sc[4], sh[4];
    #pragma unroll
    for (int r = 0; r < 4; ++r) {
      int o = m0 + 64*wr + 16*mi + 4*lg + r;
      float s = gw[o] * rsqrtf(vw[o] + BNEPS);
      sc[r] = s; sh[r] = bw[o] - mw[o]*s;
    }
    #pragma unroll
    for (int ni = 0; ni < 2; ++ni) {
      int n = n0 + 32*wc + 16*ni + ln;
      if (n >= NTOK) continue;
      #pragma unroll
      for (int r = 0; r < 4; ++r) {
        int o = m0 + 64*wr + 16*mi + 4*lg + r;
        out[((size_t)b*DIMC + o)*NTOK + n] = hswish(acc[mi][ni][r]*sc[r] + sh[r]);
      }
    }
  }
}

extern "C" void kernel_launch(void* const* d_in, const int* in_sizes, int n_in,
                              void* d_out, int out_size, void* d_ws, size_t ws_size,
                              hipStream_t stream)
{
  const float* x  = (const float*)d_in[0];
  const float* qw = (const float*)d_in[1];
  const float* qg = (const float*)d_in[2];
  const float* qb_ = (const float*)d_in[3];
  const float* qm = (const float*)d_in[4];
  const float* qv = (const float*)d_in[5];
  const float* ab = (const float*)d_in[6];
  const float* pw = (const float*)d_in[7];
  const float* pg = (const float*)d_in[8];
  const float* pb = (const float*)d_in[9];
  const float* pm = (const float*)d_in[10];
  const float* pv = (const float*)d_in[11];
  float* out = (float*)d_out;

  uint16_t* qwh = (uint16_t*)d_ws;
  uint16_t* pwh = qwh + (size_t)HQKV * DIMC;
  uint16_t* dyn = pwh + (size_t)DIMC * DHTOT;
  const size_t fixed_bytes = ((size_t)HQKV*DIMC + (size_t)DIMC*DHTOT) * 2;

  const size_t XT_B = (size_t)NTOK * DIMC;      // 301056
  const size_t QK_B = (size_t)8 * NTOK * KD;    // 200704
  const size_t V_B  = (size_t)8 * DV * NTOK;    // 802816
  const size_t A2_B = (size_t)NTOK * DHTOT;     // 802816
  const size_t PER_B = XT_B + 2*QK_B + V_B + A2_B;

  size_t avail = (ws_size > fixed_bytes) ? (ws_size - fixed_bytes) : 0;
  int nb = (int)(avail / (PER_B * 2));
  if (nb > BATCH) nb = BATCH;
  if (nb < 1) nb = 1;

  uint16_t* xTb  = dyn;
  uint16_t* qbuf = xTb  + (size_t)nb * XT_B;
  uint16_t* kbuf = qbuf + (size_t)nb * QK_B;
  uint16_t* vbuf = kbuf + (size_t)nb * QK_B;
  uint16_t* a2   = vbuf + (size_t)nb * V_B;

  convert_w<<<960, 256, 0, stream>>>(qw, pw, qwh, pwh);

  for (int b0 = 0; b0 < BATCH; b0 += nb) {
    int cb = BATCH - b0; if (cb > nb) cb = nb;
    const float* xb = x + (size_t)b0 * DIMC * NTOK;
    float* ob = out + (size_t)b0 * DIMC * NTOK;

    transpose_x<<<dim3(25, 12, cb), 256, 0, stream>>>(xb, xTb);
    qkv_gemm<<<dim3(13, 12, cb), 256, 0, stream>>>(qwh, xTb, qg, qb_, qm, qv,
                                                   qbuf, kbuf, vbuf);
    attn_kernel<<<dim3(25, cb * 8), 128, 0, stream>>>(qbuf, kbuf, vbuf, ab, a2);
    proj_gemm<<<dim3(13, 3, cb), 256, 0, stream>>>(pwh, a2, pg, pb, pm, pv, ob);
  }
}